// Round 3
// baseline (2793.535 us; speedup 1.0000x reference)
//
#include <hip/hip_runtime.h>
#include <math.h>

#define NN 100000
#define NB 256        // coarse buckets
#define RANGE 392     // nodes per bucket (256*392 = 100352 >= 100000)
#define HR 196        // half-range: one agg block owns 196 nodes
#define CAP 56        // staging entries per bucket per block
#define BCAP 13824    // bucket capacity (mean 12544, sigma ~112 -> 11 sigma)
#define NBLK_PART 520

// ---------------- partition: edges -> 256 dst-range buckets ----------------
// Entry = (src << 9) | (dst - bucket*392)  (17b + 9b = 26b, fits u32).
// LDS write-combining: stage per bucket, flush as wave-chunked contiguous
// global writes via one atomic reservation per (block,bucket) -> full lines
// instead of R2-scatter's 196MB of partial-line writebacks.

__global__ __launch_bounds__(256) void partition_kernel(const int* __restrict__ src,
                                                        const int* __restrict__ dst,
                                                        int* __restrict__ bcur,
                                                        unsigned* __restrict__ bkt, int E) {
    __shared__ unsigned stage[NB * CAP];
    __shared__ int lcnt[NB];
    for (int i = threadIdx.x; i < NB; i += 256) lcnt[i] = 0;
    __syncthreads();

    const int nq = E >> 2;
    const int stride = gridDim.x * blockDim.x;
    for (int q = blockIdx.x * blockDim.x + threadIdx.x; q < nq; q += stride) {
        const int4 s4 = ((const int4*)src)[q];
        const int4 d4 = ((const int4*)dst)[q];
#pragma unroll
        for (int k = 0; k < 4; k++) {
            const int s = (&s4.x)[k];
            const int d = (&d4.x)[k];
            const unsigned b = (unsigned)d / RANGE;
            const unsigned ent = ((unsigned)s << 9) | ((unsigned)d - b * RANGE);
            const int slot = atomicAdd(&lcnt[b], 1);
            if (slot < CAP) {
                stage[b * CAP + slot] = ent;
            } else {                       // rare overflow: direct global path
                const int pos = atomicAdd(&bcur[b], 1);
                if (pos < BCAP) bkt[(size_t)b * BCAP + pos] = ent;
            }
        }
    }
    // tail edges (E % 4)
    const int gid = blockIdx.x * blockDim.x + threadIdx.x;
    if (gid < (E & 3)) {
        const int e = (E & ~3) + gid;
        const int s = src[e], d = dst[e];
        const unsigned b = (unsigned)d / RANGE;
        const unsigned ent = ((unsigned)s << 9) | ((unsigned)d - b * RANGE);
        const int pos = atomicAdd(&bcur[b], 1);
        if (pos < BCAP) bkt[(size_t)b * BCAP + pos] = ent;
    }
    __syncthreads();

    // flush: one wave per bucket, contiguous chunk write
    const int w = threadIdx.x >> 6, l = threadIdx.x & 63;
    for (int b = w; b < NB; b += 4) {
        const int cnt = min(lcnt[b], CAP);
        int base = 0;
        if (l == 0 && cnt > 0) base = atomicAdd(&bcur[b], cnt);
        base = __shfl(base, 0);
        for (int i = l; i < cnt; i += 64) {
            const int pos = base + i;
            if (pos < BCAP) bkt[(size_t)b * BCAP + pos] = stage[b * CAP + i];
        }
    }
}

// ---------------- per-node degree -> dinv, from buckets ----------------

__global__ __launch_bounds__(256) void dinv_kernel(const int* __restrict__ bcur,
                                                   const unsigned* __restrict__ bkt,
                                                   float* __restrict__ dinv, int n) {
    __shared__ int cntS[RANGE];
    const int b = blockIdx.x;
    for (int i = threadIdx.x; i < RANGE; i += 256) cntS[i] = 0;
    __syncthreads();
    const unsigned* eb = bkt + (size_t)b * BCAP;
    const int m = min(bcur[b], BCAP);
    for (int i = threadIdx.x; i < m; i += 256) atomicAdd(&cntS[eb[i] & 511], 1);
    __syncthreads();
    for (int i = threadIdx.x; i < RANGE; i += 256) {
        const int node = b * RANGE + i;
        if (node < n) dinv[node] = rsqrtf((float)cntS[i] + 1.0f);  // +1 self-loop
    }
}

// ---------------- GEMM: y[r] = (x[r] @ W) * dinv[r]  (unchanged from R2) ----------------

template <int K, int C>
__global__ __launch_bounds__(256, 3) void gemm_kernel(const float* __restrict__ x,
                                                      const float* __restrict__ W,
                                                      const float* __restrict__ dinv,
                                                      float* __restrict__ y, int n) {
    constexpr int C4 = C / 4;
    const int lane = threadIdx.x & 63;
    const int wave = (blockIdx.x * blockDim.x + threadIdx.x) >> 6;
    const int nwaves = (gridDim.x * blockDim.x) >> 6;
    const int ntiles = (n + 63) >> 6;

    for (int tile = wave; tile < ntiles; tile += nwaves) {
        const int r = tile * 64 + lane;
        const int rr = (r < n) ? r : (n - 1);
        const float* __restrict__ xr = x + (size_t)rr * K;

        float4 acc[C4];
#pragma unroll
        for (int i = 0; i < C4; i++) acc[i] = make_float4(0.f, 0.f, 0.f, 0.f);

        for (int k = 0; k < K; k += 4) {
            const float4 xk = *(const float4*)(xr + k);
            const float* __restrict__ w0 = W + (size_t)k * C;
#pragma unroll
            for (int kk = 0; kk < 4; kk++) {
                const float xv = (kk == 0) ? xk.x : (kk == 1) ? xk.y : (kk == 2) ? xk.z : xk.w;
                const float4* __restrict__ wr = (const float4*)(w0 + kk * C);
#pragma unroll
                for (int i = 0; i < C4; i++) {
                    const float4 w = wr[i];
                    acc[i].x = fmaf(xv, w.x, acc[i].x);
                    acc[i].y = fmaf(xv, w.y, acc[i].y);
                    acc[i].z = fmaf(xv, w.z, acc[i].z);
                    acc[i].w = fmaf(xv, w.w, acc[i].w);
                }
            }
        }
        if (r < n) {
            const float di = dinv[r];
            float4* __restrict__ yr = (float4*)(y + (size_t)r * C);
#pragma unroll
            for (int i = 0; i < C4; i++) {
                float4 v;
                v.x = acc[i].x * di; v.y = acc[i].y * di;
                v.z = acc[i].z * di; v.w = acc[i].w * di;
                yr[i] = v;
            }
        }
    }
}

// ---------------- Aggregation via LDS accumulators, C=64 (+bias, ReLU) ----------------
// Block owns half a bucket (196 nodes). acc[196][65] (pad 65 -> conflict-free).
// Scans the coarse bucket's entry stream; filters its half; 4 edges in flight.

__global__ __launch_bounds__(1024) void agg64_kernel(const float* __restrict__ y,
                                                     const int* __restrict__ bcur,
                                                     const unsigned* __restrict__ bkt,
                                                     const float* __restrict__ dinv,
                                                     const float* __restrict__ bias,
                                                     float* __restrict__ out, int n) {
    __shared__ float acc[HR * 65];
    const int cb = blockIdx.x >> 1;
    const int half = blockIdx.x & 1;
    const int node0 = cb * RANGE + half * HR;
    const int lo = half * HR;
    const int tid = threadIdx.x, l = tid & 63, w = tid >> 6;  // 16 waves

    for (int i = tid; i < HR * 65; i += 1024) acc[i] = 0.f;
    __syncthreads();

    const unsigned* eb = bkt + (size_t)cb * BCAP;
    const int m = min(bcur[cb], BCAP);

    for (int base = w * 64; base < m; base += 1024) {
        const int mm = min(64, m - base);
        const int ent = (l < mm) ? (int)eb[base + l] : 0;
        for (int j = 0; j < mm; j += 4) {
            float v[4];
            int dl[4];
            bool ok[4];
#pragma unroll
            for (int k = 0; k < 4; k++) {
                const int jj = j + k;
                const int e = __shfl(ent, jj < 63 ? jj : 63);
                const int within = e & 511;
                ok[k] = (jj < mm) && (within >= lo) && (within < lo + HR);
                dl[k] = within - lo;
                const int s = e >> 9;
                v[k] = ok[k] ? y[(size_t)s * 64 + l] : 0.f;
            }
#pragma unroll
            for (int k = 0; k < 4; k++)
                if (ok[k]) atomicAdd(&acc[dl[k] * 65 + l], v[k]);
        }
    }
    __syncthreads();

    const float bv = bias[l];
    for (int nl = w; nl < HR; nl += 16) {
        const int node = node0 + nl;
        if (node >= n) break;
        const float a = acc[nl * 65 + l] + y[(size_t)node * 64 + l];
        out[(size_t)node * 64 + l] = fmaxf(a * dinv[node] + bv, 0.f);
    }
}

// ---------------- Aggregation C=40 (+bias) fused with log_softmax ----------------

__global__ __launch_bounds__(1024) void agg40_lsm_kernel(const float* __restrict__ y,
                                                         const int* __restrict__ bcur,
                                                         const unsigned* __restrict__ bkt,
                                                         const float* __restrict__ dinv,
                                                         const float* __restrict__ bias,
                                                         float* __restrict__ out, int n) {
    __shared__ float acc[HR * 41];
    const int cb = blockIdx.x >> 1;
    const int half = blockIdx.x & 1;
    const int node0 = cb * RANGE + half * HR;
    const int lo = half * HR;
    const int tid = threadIdx.x, l = tid & 63, w = tid >> 6;

    for (int i = tid; i < HR * 41; i += 1024) acc[i] = 0.f;
    __syncthreads();

    const unsigned* eb = bkt + (size_t)cb * BCAP;
    const int m = min(bcur[cb], BCAP);
    const bool lact = (l < 40);

    for (int base = w * 64; base < m; base += 1024) {
        const int mm = min(64, m - base);
        const int ent = (l < mm) ? (int)eb[base + l] : 0;
        for (int j = 0; j < mm; j += 4) {
            float v[4];
            int dl[4];
            bool ok[4];
#pragma unroll
            for (int k = 0; k < 4; k++) {
                const int jj = j + k;
                const int e = __shfl(ent, jj < 63 ? jj : 63);
                const int within = e & 511;
                ok[k] = lact && (jj < mm) && (within >= lo) && (within < lo + HR);
                dl[k] = within - lo;
                const int s = e >> 9;
                v[k] = ok[k] ? y[(size_t)s * 40 + l] : 0.f;
            }
#pragma unroll
            for (int k = 0; k < 4; k++)
                if (ok[k]) atomicAdd(&acc[dl[k] * 41 + l], v[k]);
        }
    }
    __syncthreads();

    const float bv = lact ? bias[l] : 0.f;
    for (int nl = w; nl < HR; nl += 16) {
        const int node = node0 + nl;
        if (node >= n) break;
        float h = 0.f;
        if (lact) h = (acc[nl * 41 + l] + y[(size_t)node * 40 + l]) * dinv[node] + bv;
        float mx = lact ? h : -INFINITY;
#pragma unroll
        for (int off = 1; off < 64; off <<= 1) mx = fmaxf(mx, __shfl_xor(mx, off));
        float es = lact ? __expf(h - mx) : 0.f;
#pragma unroll
        for (int off = 1; off < 64; off <<= 1) es += __shfl_xor(es, off);
        const float ls = mx + __logf(es);
        if (lact) out[(size_t)node * 40 + l] = h - ls;
    }
}

// ---------------- launch ----------------

extern "C" void kernel_launch(void* const* d_in, const int* in_sizes, int n_in,
                              void* d_out, int out_size, void* d_ws, size_t ws_size,
                              hipStream_t stream) {
    const float* x  = (const float*)d_in[0];
    const int* edges = (const int*)d_in[1];
    const float* W1 = (const float*)d_in[2];
    const float* b1 = (const float*)d_in[3];
    const float* W2 = (const float*)d_in[4];
    const float* b2 = (const float*)d_in[5];
    float* out = (float*)d_out;

    const int n = NN;
    const int E = in_sizes[1] / 2;

    char* ws = (char*)d_ws;
    size_t off = 0;
    auto alloc = [&](size_t bytes) -> void* {
        void* p = ws + off;
        off += (bytes + 255) & ~(size_t)255;
        return p;
    };
    int*      bcur = (int*)alloc((size_t)NB * 4);
    unsigned* bkt  = (unsigned*)alloc((size_t)NB * BCAP * 4);
    float*    dinv = (float*)alloc((size_t)n * 4);
    float*    h1   = (float*)alloc((size_t)n * 64 * 4);
    float*    y1   = (float*)alloc((size_t)n * 64 * 4);
    float*    y2   = y1;   // y1 dead after agg64; reuse for layer-2 xw

    const int* src = edges;
    const int* dst = edges + E;

    hipMemsetAsync(bcur, 0, (size_t)NB * 4, stream);
    partition_kernel<<<NBLK_PART, 256, 0, stream>>>(src, dst, bcur, bkt, E);
    dinv_kernel<<<NB, 256, 0, stream>>>(bcur, bkt, dinv, n);

    // layer 1: y1 = (x @ W1) * dinv ; h1 = relu(agg(y1) * dinv + b1)
    gemm_kernel<256, 64><<<391, 256, 0, stream>>>(x, W1, dinv, y1, n);
    agg64_kernel<<<2 * NB, 1024, 0, stream>>>(y1, bcur, bkt, dinv, b1, h1, n);

    // layer 2: y2 = (h1 @ W2) * dinv ; out = log_softmax(agg(y2) * dinv + b2)
    gemm_kernel<64, 40><<<391, 256, 0, stream>>>(h1, W2, dinv, y2, n);
    agg40_lsm_kernel<<<2 * NB, 1024, 0, stream>>>(y2, bcur, bkt, dinv, b2, out, n);
}

// Round 4
// 537.785 us; speedup vs baseline: 5.1945x; 5.1945x over previous
//
#include <hip/hip_runtime.h>
#include <math.h>

#define NN 100000
#define NB 256        // coarse buckets
#define RANGE 392     // nodes per bucket (256*392 = 100352 >= 100000)
#define CAP 56        // staging entries per bucket per block
#define BCAP 13824    // bucket capacity (mean 12544, sigma ~112 -> 11 sigma)
#define NBLK_PART 512

// ---------------- partition: edges -> 256 dst-range buckets ----------------
// Entry = (src << 9) | (dst - bucket*392). LDS write-combining: stage per
// bucket, reserve all bases with 256 parallel atomics, flush as contiguous
// chunk writes -> full-line writebacks (R2's scatter paid 196MB of partial
// lines; this should write ~13MB).

__global__ __launch_bounds__(256) void partition_kernel(const int* __restrict__ src,
                                                        const int* __restrict__ dst,
                                                        int* __restrict__ bcur,
                                                        unsigned* __restrict__ bkt, int E) {
    __shared__ unsigned stage[NB * CAP];
    __shared__ int lcnt[NB];
    __shared__ int baseS[NB];
    for (int i = threadIdx.x; i < NB; i += 256) lcnt[i] = 0;
    __syncthreads();

    const int nq = E >> 2;
    const int stride = gridDim.x * blockDim.x;
    for (int q = blockIdx.x * blockDim.x + threadIdx.x; q < nq; q += stride) {
        const int4 s4 = ((const int4*)src)[q];
        const int4 d4 = ((const int4*)dst)[q];
#pragma unroll
        for (int k = 0; k < 4; k++) {
            const int s = (&s4.x)[k];
            const int d = (&d4.x)[k];
            const unsigned b = (unsigned)d / RANGE;
            const unsigned ent = ((unsigned)s << 9) | ((unsigned)d - b * RANGE);
            const int slot = atomicAdd(&lcnt[b], 1);
            if (slot < CAP) {
                stage[b * CAP + slot] = ent;
            } else {                       // rare overflow: direct global path
                const int pos = atomicAdd(&bcur[b], 1);
                if (pos < BCAP) bkt[(size_t)b * BCAP + pos] = ent;
            }
        }
    }
    // tail edges (E % 4)
    const int gid = blockIdx.x * blockDim.x + threadIdx.x;
    if (gid < (E & 3)) {
        const int e = (E & ~3) + gid;
        const int s = src[e], d = dst[e];
        const unsigned b = (unsigned)d / RANGE;
        const unsigned ent = ((unsigned)s << 9) | ((unsigned)d - b * RANGE);
        const int pos = atomicAdd(&bcur[b], 1);
        if (pos < BCAP) bkt[(size_t)b * BCAP + pos] = ent;
    }
    __syncthreads();

    // reserve all bucket bases in parallel (one atomic per bucket)
    if (threadIdx.x < NB) {
        const int c = min(lcnt[threadIdx.x], CAP);
        baseS[threadIdx.x] = (c > 0) ? atomicAdd(&bcur[threadIdx.x], c) : 0;
    }
    __syncthreads();

    // flush: contiguous chunk write per bucket
    const int w = threadIdx.x >> 6, l = threadIdx.x & 63;
    for (int b = w; b < NB; b += 4) {
        const int cnt = min(lcnt[b], CAP);
        const int base = baseS[b];
        for (int i = l; i < cnt; i += 64) {
            const int pos = base + i;
            if (pos < BCAP) bkt[(size_t)b * BCAP + pos] = stage[b * CAP + i];
        }
    }
}

// ---------------- per-bucket counting sort -> CSR (+deg/dinv) ----------------
// One block per bucket. Count in LDS, wave-0 scan, scatter into LDS staging,
// write back sorted src ids IN PLACE over the bucket (contiguous, coalesced).

__global__ __launch_bounds__(256) void bucket_sort_kernel(const int* __restrict__ bcur,
                                                          unsigned* __restrict__ bkt,
                                                          int* __restrict__ row_off,
                                                          int* __restrict__ deg,
                                                          float* __restrict__ dinv, int n) {
    __shared__ int sortedS[BCAP];
    __shared__ int cntS[RANGE];
    __shared__ int offS[RANGE];
    const int b = blockIdx.x;
    const int tid = threadIdx.x;
    unsigned* eb = bkt + (size_t)b * BCAP;
    const int m = min(bcur[b], BCAP);

    for (int i = tid; i < RANGE; i += 256) cntS[i] = 0;
    __syncthreads();
    for (int i = tid; i < m; i += 256) atomicAdd(&cntS[(int)(eb[i] & 511u)], 1);
    __syncthreads();

    // exclusive scan of cntS[0..RANGE) by wave 0
    if (tid < 64) {
        const int l = tid;
        int carry = 0;
        for (int base = 0; base < RANGE; base += 64) {
            const int i = base + l;
            const int c = (i < RANGE) ? cntS[i] : 0;
            int v = c;
#pragma unroll
            for (int off = 1; off < 64; off <<= 1) {
                const int t2 = __shfl_up(v, off);
                if (l >= off) v += t2;
            }
            if (i < RANGE) offS[i] = carry + v - c;
            carry += __shfl(v, 63);
        }
    }
    __syncthreads();

    // emit CSR metadata
    for (int i = tid; i < RANGE; i += 256) {
        const int node = b * RANGE + i;
        if (node < n) {
            row_off[node] = b * BCAP + offS[i];
            deg[node] = cntS[i];
            dinv[node] = rsqrtf((float)cntS[i] + 1.0f);   // +1 self-loop
        }
    }
    __syncthreads();

    // scatter into LDS (offS doubles as cursor now)
    for (int i = tid; i < m; i += 256) {
        const unsigned e = eb[i];
        const int pos = atomicAdd(&offS[(int)(e & 511u)], 1);
        sortedS[pos] = (int)(e >> 9);
    }
    __syncthreads();

    // in-place contiguous write-back (bkt segment becomes the nbr segment)
    for (int i = tid; i < m; i += 256) eb[i] = (unsigned)sortedS[i];
}

// ---------------- GEMM: y[r] = (x[r] @ W) * dinv[r]  (R2, proven) ----------------

template <int K, int C>
__global__ __launch_bounds__(256, 3) void gemm_kernel(const float* __restrict__ x,
                                                      const float* __restrict__ W,
                                                      const float* __restrict__ dinv,
                                                      float* __restrict__ y, int n) {
    constexpr int C4 = C / 4;
    const int lane = threadIdx.x & 63;
    const int wave = (blockIdx.x * blockDim.x + threadIdx.x) >> 6;
    const int nwaves = (gridDim.x * blockDim.x) >> 6;
    const int ntiles = (n + 63) >> 6;

    for (int tile = wave; tile < ntiles; tile += nwaves) {
        const int r = tile * 64 + lane;
        const int rr = (r < n) ? r : (n - 1);
        const float* __restrict__ xr = x + (size_t)rr * K;

        float4 acc[C4];
#pragma unroll
        for (int i = 0; i < C4; i++) acc[i] = make_float4(0.f, 0.f, 0.f, 0.f);

        for (int k = 0; k < K; k += 4) {
            const float4 xk = *(const float4*)(xr + k);
            const float* __restrict__ w0 = W + (size_t)k * C;
#pragma unroll
            for (int kk = 0; kk < 4; kk++) {
                const float xv = (kk == 0) ? xk.x : (kk == 1) ? xk.y : (kk == 2) ? xk.z : xk.w;
                const float4* __restrict__ wr = (const float4*)(w0 + kk * C);
#pragma unroll
                for (int i = 0; i < C4; i++) {
                    const float4 w = wr[i];
                    acc[i].x = fmaf(xv, w.x, acc[i].x);
                    acc[i].y = fmaf(xv, w.y, acc[i].y);
                    acc[i].z = fmaf(xv, w.z, acc[i].z);
                    acc[i].w = fmaf(xv, w.w, acc[i].w);
                }
            }
        }
        if (r < n) {
            const float di = dinv[r];
            float4* __restrict__ yr = (float4*)(y + (size_t)r * C);
#pragma unroll
            for (int i = 0; i < C4; i++) {
                float4 v;
                v.x = acc[i].x * di; v.y = acc[i].y * di;
                v.z = acc[i].z * di; v.w = acc[i].w * di;
                yr[i] = v;
            }
        }
    }
}

// ---------------- Aggregation, C=64 (+bias, ReLU) ----------------
// One wave per node, 4 groups x 16 lanes x float4; 2 phases unrolled ->
// 8 edges (2KB) in flight per wave. Loads unconditional (clamped-safe),
// accumulate predicated (no branch around loads).

__global__ __launch_bounds__(256) void agg64_kernel(const float* __restrict__ y,
                                                    const int* __restrict__ row_off,
                                                    const int* __restrict__ deg,
                                                    const unsigned* __restrict__ nbr,
                                                    const float* __restrict__ dinv,
                                                    const float* __restrict__ b,
                                                    float* __restrict__ out, int n) {
    int node = blockIdx.x * 4 + (threadIdx.x >> 6);
    if (node >= n) return;
    const int l = threadIdx.x & 63;
    const int g = l >> 4;           // 0..3
    const int ci = (l & 15) << 2;   // 0,4,...,60

    const int start = row_off[node];
    const int dg = deg[node];

    float4 acc = make_float4(0.f, 0.f, 0.f, 0.f);
    for (int base = 0; base < dg; base += 64) {
        const int m = min(64, dg - base);
        const int idx = (l < m) ? (int)nbr[start + base + l] : 0;
        for (int j0 = 0; j0 < m; j0 += 8) {
            const int jA = j0 + g;          // <= 59+? max 56+3 = 59
            const int jB = j0 + 4 + g;      // max 63
            const int sA = __shfl(idx, jA);
            const int sB = __shfl(idx, jB);
            const bool okA = jA < m;
            const bool okB = jB < m;
            const float4 vA = *(const float4*)(y + (size_t)sA * 64 + ci);
            const float4 vB = *(const float4*)(y + (size_t)sB * 64 + ci);
            acc.x += okA ? vA.x : 0.f; acc.y += okA ? vA.y : 0.f;
            acc.z += okA ? vA.z : 0.f; acc.w += okA ? vA.w : 0.f;
            acc.x += okB ? vB.x : 0.f; acc.y += okB ? vB.y : 0.f;
            acc.z += okB ? vB.z : 0.f; acc.w += okB ? vB.w : 0.f;
        }
    }
#pragma unroll
    for (int off = 16; off < 64; off <<= 1) {
        acc.x += __shfl_xor(acc.x, off);
        acc.y += __shfl_xor(acc.y, off);
        acc.z += __shfl_xor(acc.z, off);
        acc.w += __shfl_xor(acc.w, off);
    }
    if (l < 16) {
        const float4 self = *(const float4*)(y + (size_t)node * 64 + ci);
        const float di = dinv[node];
        const float4 bv = *(const float4*)(b + ci);
        float4 r;
        r.x = fmaxf((acc.x + self.x) * di + bv.x, 0.f);
        r.y = fmaxf((acc.y + self.y) * di + bv.y, 0.f);
        r.z = fmaxf((acc.z + self.z) * di + bv.z, 0.f);
        r.w = fmaxf((acc.w + self.w) * di + bv.w, 0.f);
        *(float4*)(out + (size_t)node * 64 + ci) = r;
    }
}

// ---------------- Aggregation, C=40 (+bias) fused with log_softmax ----------------
// 6 groups x 10 lanes x float4 (lanes 60..63 idle); 2 phases -> 12 edges/iter.

__global__ __launch_bounds__(256) void agg40_lsm_kernel(const float* __restrict__ y,
                                                        const int* __restrict__ row_off,
                                                        const int* __restrict__ deg,
                                                        const unsigned* __restrict__ nbr,
                                                        const float* __restrict__ dinv,
                                                        const float* __restrict__ b,
                                                        float* __restrict__ out, int n) {
    int node = blockIdx.x * 4 + (threadIdx.x >> 6);
    if (node >= n) return;
    const int l = threadIdx.x & 63;
    const int g = l / 10;           // 0..6 (6 => idle)
    const int ci = (l % 10) * 4;    // 0,4,...,36
    const bool act = (g < 6);

    const int start = row_off[node];
    const int dg = deg[node];

    float4 acc = make_float4(0.f, 0.f, 0.f, 0.f);
    for (int base = 0; base < dg; base += 64) {
        const int m = min(64, dg - base);
        const int idx = (l < m) ? (int)nbr[start + base + l] : 0;
        for (int j0 = 0; j0 < m; j0 += 12) {
            const int jA = j0 + g;
            const int jB = j0 + 6 + g;
            const int sA = __shfl(idx, jA < 63 ? jA : 63);
            const int sB = __shfl(idx, jB < 63 ? jB : 63);
            const bool okA = act && (jA < m);
            const bool okB = act && (jB < m);
            const float4 vA = *(const float4*)(y + (size_t)sA * 40 + ci);
            const float4 vB = *(const float4*)(y + (size_t)sB * 40 + ci);
            acc.x += okA ? vA.x : 0.f; acc.y += okA ? vA.y : 0.f;
            acc.z += okA ? vA.z : 0.f; acc.w += okA ? vA.w : 0.f;
            acc.x += okB ? vB.x : 0.f; acc.y += okB ? vB.y : 0.f;
            acc.z += okB ? vB.z : 0.f; acc.w += okB ? vB.w : 0.f;
        }
    }
    // reduce groups 1..5 into group 0
    float4 tot = acc;
#pragma unroll
    for (int k = 1; k < 6; k++) {
        const int sl = l + k * 10;
        tot.x += __shfl(acc.x, sl & 63);
        tot.y += __shfl(acc.y, sl & 63);
        tot.z += __shfl(acc.z, sl & 63);
        tot.w += __shfl(acc.w, sl & 63);
    }

    const float di = dinv[node];
    const float4 self = *(const float4*)(y + (size_t)node * 40 + ci);
    const float4 bv = *(const float4*)(b + ci);
    float4 h;
    h.x = (tot.x + self.x) * di + bv.x;
    h.y = (tot.y + self.y) * di + bv.y;
    h.z = (tot.z + self.z) * di + bv.z;
    h.w = (tot.w + self.w) * di + bv.w;

    float mx = (l < 10) ? fmaxf(fmaxf(h.x, h.y), fmaxf(h.z, h.w)) : -INFINITY;
#pragma unroll
    for (int off = 8; off > 0; off >>= 1) mx = fmaxf(mx, __shfl_xor(mx, off, 16));
    float es = (l < 10)
                   ? (expf(h.x - mx) + expf(h.y - mx) + expf(h.z - mx) + expf(h.w - mx))
                   : 0.f;
#pragma unroll
    for (int off = 8; off > 0; off >>= 1) es += __shfl_xor(es, off, 16);
    const float ls = mx + logf(es);

    if (l < 10) {
        float4 o;
        o.x = h.x - ls; o.y = h.y - ls; o.z = h.z - ls; o.w = h.w - ls;
        *(float4*)(out + (size_t)node * 40 + ci) = o;
    }
}

// ---------------- launch ----------------

extern "C" void kernel_launch(void* const* d_in, const int* in_sizes, int n_in,
                              void* d_out, int out_size, void* d_ws, size_t ws_size,
                              hipStream_t stream) {
    const float* x  = (const float*)d_in[0];
    const int* edges = (const int*)d_in[1];
    const float* W1 = (const float*)d_in[2];
    const float* b1 = (const float*)d_in[3];
    const float* W2 = (const float*)d_in[4];
    const float* b2 = (const float*)d_in[5];
    float* out = (float*)d_out;

    const int n = NN;
    const int E = in_sizes[1] / 2;

    char* ws = (char*)d_ws;
    size_t off = 0;
    auto alloc = [&](size_t bytes) -> void* {
        void* p = ws + off;
        off += (bytes + 255) & ~(size_t)255;
        return p;
    };
    int*      bcur    = (int*)alloc((size_t)NB * 4);
    unsigned* bkt     = (unsigned*)alloc((size_t)NB * BCAP * 4);  // becomes nbr after sort
    int*      row_off = (int*)alloc((size_t)n * 4);
    int*      deg     = (int*)alloc((size_t)n * 4);
    float*    dinv    = (float*)alloc((size_t)n * 4);
    float*    h1      = (float*)alloc((size_t)n * 64 * 4);
    float*    y1      = (float*)alloc((size_t)n * 64 * 4);
    float*    y2      = y1;   // y1 dead after agg64; reuse for layer-2 xw

    const int* src = edges;
    const int* dst = edges + E;

    hipMemsetAsync(bcur, 0, (size_t)NB * 4, stream);
    partition_kernel<<<NBLK_PART, 256, 0, stream>>>(src, dst, bcur, bkt, E);
    bucket_sort_kernel<<<NB, 256, 0, stream>>>(bcur, bkt, row_off, deg, dinv, n);

    // layer 1: y1 = (x @ W1) * dinv ; h1 = relu(agg(y1) * dinv + b1)
    gemm_kernel<256, 64><<<391, 256, 0, stream>>>(x, W1, dinv, y1, n);
    agg64_kernel<<<(n + 3) / 4, 256, 0, stream>>>(y1, row_off, deg, bkt, dinv, b1, h1, n);

    // layer 2: y2 = (h1 @ W2) * dinv ; out = log_softmax(agg(y2) * dinv + b2)
    gemm_kernel<64, 40><<<391, 256, 0, stream>>>(h1, W2, dinv, y2, n);
    agg40_lsm_kernel<<<(n + 3) / 4, 256, 0, stream>>>(y2, row_off, deg, bkt, dinv, b2, out, n);
}

// Round 5
// 471.238 us; speedup vs baseline: 5.9281x; 1.1412x over previous
//
#include <hip/hip_runtime.h>
#include <math.h>

#define NN 100000
#define NB 256        // coarse buckets
#define RANGE 392     // nodes per bucket (256*392 = 100352 >= 100000)
#define CAP 56        // staging entries per bucket per block
#define BCAP 13824    // bucket capacity (mean 12544, sigma ~112 -> 11 sigma)
#define NBLK_PART 512

// ---------------- partition: edges -> 256 dst-range buckets ----------------
// Entry = (src << 9) | (dst - bucket*392). LDS write-combining: stage per
// bucket, reserve bases with parallel atomics, flush contiguous chunks.

__global__ __launch_bounds__(256) void partition_kernel(const int* __restrict__ src,
                                                        const int* __restrict__ dst,
                                                        int* __restrict__ bcur,
                                                        unsigned* __restrict__ bkt, int E) {
    __shared__ unsigned stage[NB * CAP];
    __shared__ int lcnt[NB];
    __shared__ int baseS[NB];
    for (int i = threadIdx.x; i < NB; i += 256) lcnt[i] = 0;
    __syncthreads();

    const int nq = E >> 2;
    const int stride = gridDim.x * blockDim.x;
    for (int q = blockIdx.x * blockDim.x + threadIdx.x; q < nq; q += stride) {
        const int4 s4 = ((const int4*)src)[q];
        const int4 d4 = ((const int4*)dst)[q];
#pragma unroll
        for (int k = 0; k < 4; k++) {
            const int s = (&s4.x)[k];
            const int d = (&d4.x)[k];
            const unsigned b = (unsigned)d / RANGE;
            const unsigned ent = ((unsigned)s << 9) | ((unsigned)d - b * RANGE);
            const int slot = atomicAdd(&lcnt[b], 1);
            if (slot < CAP) {
                stage[b * CAP + slot] = ent;
            } else {                       // rare overflow: direct global path
                const int pos = atomicAdd(&bcur[b], 1);
                if (pos < BCAP) bkt[(size_t)b * BCAP + pos] = ent;
            }
        }
    }
    // tail edges (E % 4)
    const int gid = blockIdx.x * blockDim.x + threadIdx.x;
    if (gid < (E & 3)) {
        const int e = (E & ~3) + gid;
        const int s = src[e], d = dst[e];
        const unsigned b = (unsigned)d / RANGE;
        const unsigned ent = ((unsigned)s << 9) | ((unsigned)d - b * RANGE);
        const int pos = atomicAdd(&bcur[b], 1);
        if (pos < BCAP) bkt[(size_t)b * BCAP + pos] = ent;
    }
    __syncthreads();

    // reserve all bucket bases in parallel (one atomic per bucket)
    if (threadIdx.x < NB) {
        const int c = min(lcnt[threadIdx.x], CAP);
        baseS[threadIdx.x] = (c > 0) ? atomicAdd(&bcur[threadIdx.x], c) : 0;
    }
    __syncthreads();

    // flush: contiguous chunk write per bucket
    const int w = threadIdx.x >> 6, l = threadIdx.x & 63;
    for (int b = w; b < NB; b += 4) {
        const int cnt = min(lcnt[b], CAP);
        const int base = baseS[b];
        for (int i = l; i < cnt; i += 64) {
            const int pos = base + i;
            if (pos < BCAP) bkt[(size_t)b * BCAP + pos] = stage[b * CAP + i];
        }
    }
}

// ---------------- per-bucket counting sort -> CSR (+deg/dinv) ----------------

__global__ __launch_bounds__(256) void bucket_sort_kernel(const int* __restrict__ bcur,
                                                          unsigned* __restrict__ bkt,
                                                          int* __restrict__ row_off,
                                                          int* __restrict__ deg,
                                                          float* __restrict__ dinv, int n) {
    __shared__ int sortedS[BCAP];
    __shared__ int cntS[RANGE];
    __shared__ int offS[RANGE];
    const int b = blockIdx.x;
    const int tid = threadIdx.x;
    unsigned* eb = bkt + (size_t)b * BCAP;
    const int m = min(bcur[b], BCAP);

    for (int i = tid; i < RANGE; i += 256) cntS[i] = 0;
    __syncthreads();
    for (int i = tid; i < m; i += 256) atomicAdd(&cntS[(int)(eb[i] & 511u)], 1);
    __syncthreads();

    // exclusive scan of cntS[0..RANGE) by wave 0
    if (tid < 64) {
        const int l = tid;
        int carry = 0;
        for (int base = 0; base < RANGE; base += 64) {
            const int i = base + l;
            const int c = (i < RANGE) ? cntS[i] : 0;
            int v = c;
#pragma unroll
            for (int off = 1; off < 64; off <<= 1) {
                const int t2 = __shfl_up(v, off);
                if (l >= off) v += t2;
            }
            if (i < RANGE) offS[i] = carry + v - c;
            carry += __shfl(v, 63);
        }
    }
    __syncthreads();

    // emit CSR metadata
    for (int i = tid; i < RANGE; i += 256) {
        const int node = b * RANGE + i;
        if (node < n) {
            row_off[node] = b * BCAP + offS[i];
            deg[node] = cntS[i];
            dinv[node] = rsqrtf((float)cntS[i] + 1.0f);   // +1 self-loop
        }
    }
    __syncthreads();

    // scatter into LDS (offS doubles as cursor now)
    for (int i = tid; i < m; i += 256) {
        const unsigned e = eb[i];
        const int pos = atomicAdd(&offS[(int)(e & 511u)], 1);
        sortedS[pos] = (int)(e >> 9);
    }
    __syncthreads();

    // in-place contiguous write-back (bkt segment becomes the nbr segment)
    for (int i = tid; i < m; i += 256) eb[i] = (unsigned)sortedS[i];
}

// ---------------- GEMM: y[r] = (x[r] @ W) * dinv[r] ----------------
// LDS-tiled, register-blocked. 128 rows/block, 128 threads (2 waves),
// thread tile 8 rows x 8 channels (64 acc). x staged TRANSPOSED in LDS
// (xs[k][row], stride 132: 16B-aligned b128 reads, ~2-way banks);
// W staged as ws[k][64] (C zero-padded to 64). All global loads coalesced
// float4. Per k: 4 ds_read_b128 + 64 FMA -> LDS-pipe-bound ~31us for gemm1.

template <int K, int CREAL>
__global__ __launch_bounds__(128) void gemm_kernel(const float* __restrict__ x,
                                                   const float* __restrict__ W,
                                                   const float* __restrict__ dinv,
                                                   float* __restrict__ y, int n) {
    constexpr int KC = 32;
    constexpr int XSTR = 132;            // 128 rows + pad (multiple of 4 for b128 align)
    __shared__ float xs[KC * XSTR];      // 16.9 KB
    __shared__ float ws[KC * 64];        // 8 KB
    const int t = threadIdx.x;
    const int ct = t & 7;                // channel group: c0 = ct*8
    const int c0 = ct * 8;
    const int rg = t >> 3;               // row group 0..15: r0 = rg*8
    const int r0 = rg * 8;
    const int row0 = blockIdx.x * 128;

    float acc[8][8];
#pragma unroll
    for (int i = 0; i < 8; i++)
#pragma unroll
        for (int j = 0; j < 8; j++) acc[i][j] = 0.f;

    for (int kc = 0; kc < K; kc += KC) {
        __syncthreads();
        // stage x chunk: rows 0..127, k kc..kc+31, transposed into xs[k][row]
#pragma unroll
        for (int p = 0; p < 8; p++) {
            const int idx = t + p * 128;         // 0..1023
            const int kq = idx & 7;              // k-quad within chunk
            const int row = idx >> 3;            // 0..127
            const int gr = min(row0 + row, n - 1);
            const float4 g = *(const float4*)(x + (size_t)gr * K + kc + kq * 4);
            xs[(kq * 4 + 0) * XSTR + row] = g.x;
            xs[(kq * 4 + 1) * XSTR + row] = g.y;
            xs[(kq * 4 + 2) * XSTR + row] = g.z;
            xs[(kq * 4 + 3) * XSTR + row] = g.w;
        }
        // stage W chunk: ws[k][c], c zero-padded to 64
#pragma unroll
        for (int p = 0; p < 4; p++) {
            const int idx = t + p * 128;         // 0..511
            const int k = idx >> 4;
            const int cq = idx & 15;
            float4 g = make_float4(0.f, 0.f, 0.f, 0.f);
            if (cq * 4 < CREAL)
                g = *(const float4*)(W + (size_t)(kc + k) * CREAL + cq * 4);
            *(float4*)(ws + k * 64 + cq * 4) = g;
        }
        __syncthreads();
        // compute
#pragma unroll 4
        for (int k = 0; k < KC; k++) {
            const float4 xa = *(const float4*)(xs + k * XSTR + r0);
            const float4 xb = *(const float4*)(xs + k * XSTR + r0 + 4);
            const float4 wa = *(const float4*)(ws + k * 64 + c0);
            const float4 wb = *(const float4*)(ws + k * 64 + c0 + 4);
            const float xr[8] = {xa.x, xa.y, xa.z, xa.w, xb.x, xb.y, xb.z, xb.w};
            const float wc[8] = {wa.x, wa.y, wa.z, wa.w, wb.x, wb.y, wb.z, wb.w};
#pragma unroll
            for (int i = 0; i < 8; i++)
#pragma unroll
                for (int j = 0; j < 8; j++) acc[i][j] = fmaf(xr[i], wc[j], acc[i][j]);
        }
    }
    // epilogue: scale by dinv, store (skip padded channels)
    if (c0 < CREAL) {
#pragma unroll
        for (int i = 0; i < 8; i++) {
            const int row = row0 + r0 + i;
            if (row < n) {
                const float di = dinv[row];
                float4 o0, o1;
                o0.x = acc[i][0] * di; o0.y = acc[i][1] * di;
                o0.z = acc[i][2] * di; o0.w = acc[i][3] * di;
                o1.x = acc[i][4] * di; o1.y = acc[i][5] * di;
                o1.z = acc[i][6] * di; o1.w = acc[i][7] * di;
                *(float4*)(y + (size_t)row * CREAL + c0) = o0;
                *(float4*)(y + (size_t)row * CREAL + c0 + 4) = o1;
            }
        }
    }
}

// ---------------- Aggregation, C=64 (+bias, ReLU) ----------------
// One wave per node, 4 groups x 16 lanes x float4; 2 phases unrolled ->
// 8 edges (2KB) in flight per wave.

__global__ __launch_bounds__(256) void agg64_kernel(const float* __restrict__ y,
                                                    const int* __restrict__ row_off,
                                                    const int* __restrict__ deg,
                                                    const unsigned* __restrict__ nbr,
                                                    const float* __restrict__ dinv,
                                                    const float* __restrict__ b,
                                                    float* __restrict__ out, int n) {
    int node = blockIdx.x * 4 + (threadIdx.x >> 6);
    if (node >= n) return;
    const int l = threadIdx.x & 63;
    const int g = l >> 4;           // 0..3
    const int ci = (l & 15) << 2;   // 0,4,...,60

    const int start = row_off[node];
    const int dg = deg[node];

    float4 acc = make_float4(0.f, 0.f, 0.f, 0.f);
    for (int base = 0; base < dg; base += 64) {
        const int m = min(64, dg - base);
        const int idx = (l < m) ? (int)nbr[start + base + l] : 0;
        for (int j0 = 0; j0 < m; j0 += 8) {
            const int jA = j0 + g;
            const int jB = j0 + 4 + g;
            const int sA = __shfl(idx, jA);
            const int sB = __shfl(idx, jB);
            const bool okA = jA < m;
            const bool okB = jB < m;
            const float4 vA = *(const float4*)(y + (size_t)sA * 64 + ci);
            const float4 vB = *(const float4*)(y + (size_t)sB * 64 + ci);
            acc.x += okA ? vA.x : 0.f; acc.y += okA ? vA.y : 0.f;
            acc.z += okA ? vA.z : 0.f; acc.w += okA ? vA.w : 0.f;
            acc.x += okB ? vB.x : 0.f; acc.y += okB ? vB.y : 0.f;
            acc.z += okB ? vB.z : 0.f; acc.w += okB ? vB.w : 0.f;
        }
    }
#pragma unroll
    for (int off = 16; off < 64; off <<= 1) {
        acc.x += __shfl_xor(acc.x, off);
        acc.y += __shfl_xor(acc.y, off);
        acc.z += __shfl_xor(acc.z, off);
        acc.w += __shfl_xor(acc.w, off);
    }
    if (l < 16) {
        const float4 self = *(const float4*)(y + (size_t)node * 64 + ci);
        const float di = dinv[node];
        const float4 bv = *(const float4*)(b + ci);
        float4 r;
        r.x = fmaxf((acc.x + self.x) * di + bv.x, 0.f);
        r.y = fmaxf((acc.y + self.y) * di + bv.y, 0.f);
        r.z = fmaxf((acc.z + self.z) * di + bv.z, 0.f);
        r.w = fmaxf((acc.w + self.w) * di + bv.w, 0.f);
        *(float4*)(out + (size_t)node * 64 + ci) = r;
    }
}

// ---------------- Aggregation, C=40 (+bias) fused with log_softmax ----------------

__global__ __launch_bounds__(256) void agg40_lsm_kernel(const float* __restrict__ y,
                                                        const int* __restrict__ row_off,
                                                        const int* __restrict__ deg,
                                                        const unsigned* __restrict__ nbr,
                                                        const float* __restrict__ dinv,
                                                        const float* __restrict__ b,
                                                        float* __restrict__ out, int n) {
    int node = blockIdx.x * 4 + (threadIdx.x >> 6);
    if (node >= n) return;
    const int l = threadIdx.x & 63;
    const int g = l / 10;           // 0..6 (6 => idle)
    const int ci = (l % 10) * 4;    // 0,4,...,36
    const bool act = (g < 6);

    const int start = row_off[node];
    const int dg = deg[node];

    float4 acc = make_float4(0.f, 0.f, 0.f, 0.f);
    for (int base = 0; base < dg; base += 64) {
        const int m = min(64, dg - base);
        const int idx = (l < m) ? (int)nbr[start + base + l] : 0;
        for (int j0 = 0; j0 < m; j0 += 12) {
            const int jA = j0 + g;
            const int jB = j0 + 6 + g;
            const int sA = __shfl(idx, jA < 63 ? jA : 63);
            const int sB = __shfl(idx, jB < 63 ? jB : 63);
            const bool okA = act && (jA < m);
            const bool okB = act && (jB < m);
            const float4 vA = *(const float4*)(y + (size_t)sA * 40 + ci);
            const float4 vB = *(const float4*)(y + (size_t)sB * 40 + ci);
            acc.x += okA ? vA.x : 0.f; acc.y += okA ? vA.y : 0.f;
            acc.z += okA ? vA.z : 0.f; acc.w += okA ? vA.w : 0.f;
            acc.x += okB ? vB.x : 0.f; acc.y += okB ? vB.y : 0.f;
            acc.z += okB ? vB.z : 0.f; acc.w += okB ? vB.w : 0.f;
        }
    }
    // reduce groups 1..5 into group 0
    float4 tot = acc;
#pragma unroll
    for (int k = 1; k < 6; k++) {
        const int sl = l + k * 10;
        tot.x += __shfl(acc.x, sl & 63);
        tot.y += __shfl(acc.y, sl & 63);
        tot.z += __shfl(acc.z, sl & 63);
        tot.w += __shfl(acc.w, sl & 63);
    }

    const float di = dinv[node];
    const float4 self = *(const float4*)(y + (size_t)node * 40 + ci);
    const float4 bv = *(const float4*)(b + ci);
    float4 h;
    h.x = (tot.x + self.x) * di + bv.x;
    h.y = (tot.y + self.y) * di + bv.y;
    h.z = (tot.z + self.z) * di + bv.z;
    h.w = (tot.w + self.w) * di + bv.w;

    float mx = (l < 10) ? fmaxf(fmaxf(h.x, h.y), fmaxf(h.z, h.w)) : -INFINITY;
#pragma unroll
    for (int off = 8; off > 0; off >>= 1) mx = fmaxf(mx, __shfl_xor(mx, off, 16));
    float es = (l < 10)
                   ? (expf(h.x - mx) + expf(h.y - mx) + expf(h.z - mx) + expf(h.w - mx))
                   : 0.f;
#pragma unroll
    for (int off = 8; off > 0; off >>= 1) es += __shfl_xor(es, off, 16);
    const float ls = mx + logf(es);

    if (l < 10) {
        float4 o;
        o.x = h.x - ls; o.y = h.y - ls; o.z = h.z - ls; o.w = h.w - ls;
        *(float4*)(out + (size_t)node * 40 + ci) = o;
    }
}

// ---------------- launch ----------------

extern "C" void kernel_launch(void* const* d_in, const int* in_sizes, int n_in,
                              void* d_out, int out_size, void* d_ws, size_t ws_size,
                              hipStream_t stream) {
    const float* x  = (const float*)d_in[0];
    const int* edges = (const int*)d_in[1];
    const float* W1 = (const float*)d_in[2];
    const float* b1 = (const float*)d_in[3];
    const float* W2 = (const float*)d_in[4];
    const float* b2 = (const float*)d_in[5];
    float* out = (float*)d_out;

    const int n = NN;
    const int E = in_sizes[1] / 2;

    char* ws = (char*)d_ws;
    size_t off = 0;
    auto alloc = [&](size_t bytes) -> void* {
        void* p = ws + off;
        off += (bytes + 255) & ~(size_t)255;
        return p;
    };
    int*      bcur    = (int*)alloc((size_t)NB * 4);
    unsigned* bkt     = (unsigned*)alloc((size_t)NB * BCAP * 4);  // becomes nbr after sort
    int*      row_off = (int*)alloc((size_t)n * 4);
    int*      deg     = (int*)alloc((size_t)n * 4);
    float*    dinv    = (float*)alloc((size_t)n * 4);
    float*    h1      = (float*)alloc((size_t)n * 64 * 4);
    float*    y1      = (float*)alloc((size_t)n * 64 * 4);
    float*    y2      = y1;   // y1 dead after agg64; reuse for layer-2 xw

    const int* src = edges;
    const int* dst = edges + E;

    hipMemsetAsync(bcur, 0, (size_t)NB * 4, stream);
    partition_kernel<<<NBLK_PART, 256, 0, stream>>>(src, dst, bcur, bkt, E);
    bucket_sort_kernel<<<NB, 256, 0, stream>>>(bcur, bkt, row_off, deg, dinv, n);

    const int gblk = (n + 127) / 128;   // 782

    // layer 1: y1 = (x @ W1) * dinv ; h1 = relu(agg(y1) * dinv + b1)
    gemm_kernel<256, 64><<<gblk, 128, 0, stream>>>(x, W1, dinv, y1, n);
    agg64_kernel<<<(n + 3) / 4, 256, 0, stream>>>(y1, row_off, deg, bkt, dinv, b1, h1, n);

    // layer 2: y2 = (h1 @ W2) * dinv ; out = log_softmax(agg(y2) * dinv + b2)
    gemm_kernel<64, 40><<<gblk, 128, 0, stream>>>(h1, W2, dinv, y2, n);
    agg40_lsm_kernel<<<(n + 3) / 4, 256, 0, stream>>>(y2, row_off, deg, bkt, dinv, b2, out, n);
}

// Round 6
// 393.466 us; speedup vs baseline: 7.0998x; 1.1977x over previous
//
#include <hip/hip_runtime.h>
#include <math.h>

#define NN 100000
#define NB 256        // coarse buckets
#define RANGE 392     // nodes per bucket (256*392 = 100352 >= 100000)
#define CAP 56        // staging entries per bucket per block
#define BCAP 13824    // bucket capacity (mean 12544, sigma ~112 -> 11 sigma)
#define NBLK_PART 512

typedef unsigned int uint;

// ---------------- partition: edges -> 256 dst-range buckets ----------------

__global__ __launch_bounds__(256) void partition_kernel(const int* __restrict__ src,
                                                        const int* __restrict__ dst,
                                                        int* __restrict__ bcur,
                                                        unsigned* __restrict__ bkt, int E) {
    __shared__ unsigned stage[NB * CAP];
    __shared__ int lcnt[NB];
    __shared__ int baseS[NB];
    for (int i = threadIdx.x; i < NB; i += 256) lcnt[i] = 0;
    __syncthreads();

    const int nq = E >> 2;
    const int stride = gridDim.x * blockDim.x;
    for (int q = blockIdx.x * blockDim.x + threadIdx.x; q < nq; q += stride) {
        const int4 s4 = ((const int4*)src)[q];
        const int4 d4 = ((const int4*)dst)[q];
#pragma unroll
        for (int k = 0; k < 4; k++) {
            const int s = (&s4.x)[k];
            const int d = (&d4.x)[k];
            const unsigned b = (unsigned)d / RANGE;
            const unsigned ent = ((unsigned)s << 9) | ((unsigned)d - b * RANGE);
            const int slot = atomicAdd(&lcnt[b], 1);
            if (slot < CAP) {
                stage[b * CAP + slot] = ent;
            } else {                       // rare overflow: direct global path
                const int pos = atomicAdd(&bcur[b], 1);
                if (pos < BCAP) bkt[(size_t)b * BCAP + pos] = ent;
            }
        }
    }
    // tail edges (E % 4)
    const int gid = blockIdx.x * blockDim.x + threadIdx.x;
    if (gid < (E & 3)) {
        const int e = (E & ~3) + gid;
        const int s = src[e], d = dst[e];
        const unsigned b = (unsigned)d / RANGE;
        const unsigned ent = ((unsigned)s << 9) | ((unsigned)d - b * RANGE);
        const int pos = atomicAdd(&bcur[b], 1);
        if (pos < BCAP) bkt[(size_t)b * BCAP + pos] = ent;
    }
    __syncthreads();

    // reserve all bucket bases in parallel (one atomic per bucket)
    if (threadIdx.x < NB) {
        const int c = min(lcnt[threadIdx.x], CAP);
        baseS[threadIdx.x] = (c > 0) ? atomicAdd(&bcur[threadIdx.x], c) : 0;
    }
    __syncthreads();

    // flush: contiguous chunk write per bucket
    const int w = threadIdx.x >> 6, l = threadIdx.x & 63;
    for (int b = w; b < NB; b += 4) {
        const int cnt = min(lcnt[b], CAP);
        const int base = baseS[b];
        for (int i = l; i < cnt; i += 64) {
            const int pos = base + i;
            if (pos < BCAP) bkt[(size_t)b * BCAP + pos] = stage[b * CAP + i];
        }
    }
}

// ---------------- per-bucket counting sort -> CSR (+deg/dinv) ----------------

__global__ __launch_bounds__(256) void bucket_sort_kernel(const int* __restrict__ bcur,
                                                          unsigned* __restrict__ bkt,
                                                          int* __restrict__ row_off,
                                                          int* __restrict__ deg,
                                                          float* __restrict__ dinv, int n) {
    __shared__ int sortedS[BCAP];
    __shared__ int cntS[RANGE];
    __shared__ int offS[RANGE];
    const int b = blockIdx.x;
    const int tid = threadIdx.x;
    unsigned* eb = bkt + (size_t)b * BCAP;
    const int m = min(bcur[b], BCAP);

    for (int i = tid; i < RANGE; i += 256) cntS[i] = 0;
    __syncthreads();
    for (int i = tid; i < m; i += 256) atomicAdd(&cntS[(int)(eb[i] & 511u)], 1);
    __syncthreads();

    // exclusive scan of cntS[0..RANGE) by wave 0
    if (tid < 64) {
        const int l = tid;
        int carry = 0;
        for (int base = 0; base < RANGE; base += 64) {
            const int i = base + l;
            const int c = (i < RANGE) ? cntS[i] : 0;
            int v = c;
#pragma unroll
            for (int off = 1; off < 64; off <<= 1) {
                const int t2 = __shfl_up(v, off);
                if (l >= off) v += t2;
            }
            if (i < RANGE) offS[i] = carry + v - c;
            carry += __shfl(v, 63);
        }
    }
    __syncthreads();

    // emit CSR metadata
    for (int i = tid; i < RANGE; i += 256) {
        const int node = b * RANGE + i;
        if (node < n) {
            row_off[node] = b * BCAP + offS[i];
            deg[node] = cntS[i];
            dinv[node] = rsqrtf((float)cntS[i] + 1.0f);   // +1 self-loop
        }
    }
    __syncthreads();

    // scatter into LDS (offS doubles as cursor now)
    for (int i = tid; i < m; i += 256) {
        const unsigned e = eb[i];
        const int pos = atomicAdd(&offS[(int)(e & 511u)], 1);
        sortedS[pos] = (int)(e >> 9);
    }
    __syncthreads();

    // in-place contiguous write-back (bkt segment becomes the nbr segment)
    for (int i = tid; i < m; i += 256) eb[i] = (unsigned)sortedS[i];
}

// bf16 helpers
__device__ inline uint pack_bf16(float a, float b) {
    uint ua = __float_as_uint(a), ub = __float_as_uint(b);
    ua = (ua + 0x7fffu + ((ua >> 16) & 1u)) >> 16;           // RNE, low half
    ub = (ub + 0x7fffu + ((ub >> 16) & 1u)) & 0xffff0000u;   // RNE, high half
    return ua | ub;
}
__device__ inline void acc_bf16x8(float* acc, uint4 v) {
    const uint u[4] = {v.x, v.y, v.z, v.w};
#pragma unroll
    for (int i = 0; i < 4; i++) {
        acc[2 * i]     += __uint_as_float(u[i] << 16);
        acc[2 * i + 1] += __uint_as_float(u[i] & 0xffff0000u);
    }
}

// ---------------- GEMM: ybf16[r] = (x[r] @ W) * dinv[r], padded to 64 ch ----------------
// LDS-tiled register-blocked (R5, proven). Output rows are 64 bf16 = 128 B
// (= 2 cache lines) regardless of CREAL; channels >= CREAL are zeros (from
// zero-padded W staging), which the agg epilogues mask.

template <int K, int CREAL>
__global__ __launch_bounds__(128) void gemm_kernel(const float* __restrict__ x,
                                                   const float* __restrict__ W,
                                                   const float* __restrict__ dinv,
                                                   unsigned short* __restrict__ y, int n) {
    constexpr int KC = 32;
    constexpr int XSTR = 132;
    __shared__ float xs[KC * XSTR];      // 16.9 KB
    __shared__ float ws[KC * 64];        // 8 KB
    const int t = threadIdx.x;
    const int ct = t & 7;
    const int c0 = ct * 8;
    const int rg = t >> 3;
    const int r0 = rg * 8;
    const int row0 = blockIdx.x * 128;

    float acc[8][8];
#pragma unroll
    for (int i = 0; i < 8; i++)
#pragma unroll
        for (int j = 0; j < 8; j++) acc[i][j] = 0.f;

    for (int kc = 0; kc < K; kc += KC) {
        __syncthreads();
#pragma unroll
        for (int p = 0; p < 8; p++) {
            const int idx = t + p * 128;
            const int kq = idx & 7;
            const int row = idx >> 3;
            const int gr = min(row0 + row, n - 1);
            const float4 g = *(const float4*)(x + (size_t)gr * K + kc + kq * 4);
            xs[(kq * 4 + 0) * XSTR + row] = g.x;
            xs[(kq * 4 + 1) * XSTR + row] = g.y;
            xs[(kq * 4 + 2) * XSTR + row] = g.z;
            xs[(kq * 4 + 3) * XSTR + row] = g.w;
        }
#pragma unroll
        for (int p = 0; p < 4; p++) {
            const int idx = t + p * 128;
            const int k = idx >> 4;
            const int cq = idx & 15;
            float4 g = make_float4(0.f, 0.f, 0.f, 0.f);
            if (cq * 4 < CREAL)
                g = *(const float4*)(W + (size_t)(kc + k) * CREAL + cq * 4);
            *(float4*)(ws + k * 64 + cq * 4) = g;
        }
        __syncthreads();
#pragma unroll 4
        for (int k = 0; k < KC; k++) {
            const float4 xa = *(const float4*)(xs + k * XSTR + r0);
            const float4 xb = *(const float4*)(xs + k * XSTR + r0 + 4);
            const float4 wa = *(const float4*)(ws + k * 64 + c0);
            const float4 wb = *(const float4*)(ws + k * 64 + c0 + 4);
            const float xr[8] = {xa.x, xa.y, xa.z, xa.w, xb.x, xb.y, xb.z, xb.w};
            const float wc[8] = {wa.x, wa.y, wa.z, wa.w, wb.x, wb.y, wb.z, wb.w};
#pragma unroll
            for (int i = 0; i < 8; i++)
#pragma unroll
                for (int j = 0; j < 8; j++) acc[i][j] = fmaf(xr[i], wc[j], acc[i][j]);
        }
    }
    // epilogue: scale by dinv, pack bf16 (padded channels are 0*di = 0)
#pragma unroll
    for (int i = 0; i < 8; i++) {
        const int row = row0 + r0 + i;
        if (row < n) {
            const float di = dinv[row];
            uint4 o;
            o.x = pack_bf16(acc[i][0] * di, acc[i][1] * di);
            o.y = pack_bf16(acc[i][2] * di, acc[i][3] * di);
            o.z = pack_bf16(acc[i][4] * di, acc[i][5] * di);
            o.w = pack_bf16(acc[i][6] * di, acc[i][7] * di);
            ((uint4*)(y + (size_t)row * 64))[ct] = o;
        }
    }
}

// ---------------- Aggregation, C=64 bf16 (+bias, ReLU), h1 out fp32 ----------------
// One wave per node. 8 groups x 8 lanes x uint4(=8 bf16=16B); rows are 128 B
// = 2 lines. 2 phases -> 16 edges in flight. xor-reduce over groups (8/16/32).

__global__ __launch_bounds__(256) void agg64_kernel(const unsigned short* __restrict__ y,
                                                    const int* __restrict__ row_off,
                                                    const int* __restrict__ deg,
                                                    const unsigned* __restrict__ nbr,
                                                    const float* __restrict__ dinv,
                                                    const float* __restrict__ b,
                                                    float* __restrict__ out, int n) {
    int node = blockIdx.x * 4 + (threadIdx.x >> 6);
    if (node >= n) return;
    const int l = threadIdx.x & 63;
    const int g = l >> 3;            // 0..7
    const int cq = l & 7;            // 16B chunk within row; channels cq*8..cq*8+7

    const int start = row_off[node];
    const int dg = deg[node];

    float acc[8];
#pragma unroll
    for (int i = 0; i < 8; i++) acc[i] = 0.f;

    for (int base = 0; base < dg; base += 64) {
        const int m = min(64, dg - base);
        const int idx = (l < m) ? (int)nbr[start + base + l] : 0;
        for (int j0 = 0; j0 < m; j0 += 16) {
            const int jA = j0 + g;          // <= 55
            const int jB = j0 + 8 + g;      // <= 63
            const int sA = __shfl(idx, jA);
            const int sB = __shfl(idx, jB);
            const bool okA = jA < m;
            const bool okB = jB < m;
            uint4 vA = ((const uint4*)(y + (size_t)sA * 64))[cq];
            uint4 vB = ((const uint4*)(y + (size_t)sB * 64))[cq];
            vA.x = okA ? vA.x : 0u; vA.y = okA ? vA.y : 0u;
            vA.z = okA ? vA.z : 0u; vA.w = okA ? vA.w : 0u;
            vB.x = okB ? vB.x : 0u; vB.y = okB ? vB.y : 0u;
            vB.z = okB ? vB.z : 0u; vB.w = okB ? vB.w : 0u;
            acc_bf16x8(acc, vA);
            acc_bf16x8(acc, vB);
        }
    }
    // reduce across the 8 groups
#pragma unroll
    for (int off = 8; off < 64; off <<= 1)
#pragma unroll
        for (int i = 0; i < 8; i++) acc[i] += __shfl_xor(acc[i], off);

    // self-loop + scale + bias + relu; lanes 0..7 write fp32 h1
    float self[8];
#pragma unroll
    for (int i = 0; i < 8; i++) self[i] = 0.f;
    acc_bf16x8(self, ((const uint4*)(y + (size_t)node * 64))[cq]);
    const float di = dinv[node];
    const float4 bv0 = *(const float4*)(b + cq * 8);
    const float4 bv1 = *(const float4*)(b + cq * 8 + 4);
    const float bb[8] = {bv0.x, bv0.y, bv0.z, bv0.w, bv1.x, bv1.y, bv1.z, bv1.w};
    if (l < 8) {
        float4 o0, o1;
        o0.x = fmaxf((acc[0] + self[0]) * di + bb[0], 0.f);
        o0.y = fmaxf((acc[1] + self[1]) * di + bb[1], 0.f);
        o0.z = fmaxf((acc[2] + self[2]) * di + bb[2], 0.f);
        o0.w = fmaxf((acc[3] + self[3]) * di + bb[3], 0.f);
        o1.x = fmaxf((acc[4] + self[4]) * di + bb[4], 0.f);
        o1.y = fmaxf((acc[5] + self[5]) * di + bb[5], 0.f);
        o1.z = fmaxf((acc[6] + self[6]) * di + bb[6], 0.f);
        o1.w = fmaxf((acc[7] + self[7]) * di + bb[7], 0.f);
        *(float4*)(out + (size_t)node * 64 + l * 8) = o0;
        *(float4*)(out + (size_t)node * 64 + l * 8 + 4) = o1;
    }
}

// ---------------- Aggregation C=40 (bf16 rows padded to 64) + log_softmax ----------------
// Same gather as agg64. Real channels = 40 = 5 lanes x 8; clusters cq>=5 are
// padding (zeros), masked out of the softmax with -inf.

__global__ __launch_bounds__(256) void agg40_lsm_kernel(const unsigned short* __restrict__ y,
                                                        const int* __restrict__ row_off,
                                                        const int* __restrict__ deg,
                                                        const unsigned* __restrict__ nbr,
                                                        const float* __restrict__ dinv,
                                                        const float* __restrict__ b,
                                                        float* __restrict__ out, int n) {
    int node = blockIdx.x * 4 + (threadIdx.x >> 6);
    if (node >= n) return;
    const int l = threadIdx.x & 63;
    const int g = l >> 3;
    const int cq = l & 7;
    const bool real = (cq < 5);      // channels cq*8..cq*8+7 < 40

    const int start = row_off[node];
    const int dg = deg[node];

    float acc[8];
#pragma unroll
    for (int i = 0; i < 8; i++) acc[i] = 0.f;

    for (int base = 0; base < dg; base += 64) {
        const int m = min(64, dg - base);
        const int idx = (l < m) ? (int)nbr[start + base + l] : 0;
        for (int j0 = 0; j0 < m; j0 += 16) {
            const int jA = j0 + g;
            const int jB = j0 + 8 + g;
            const int sA = __shfl(idx, jA);
            const int sB = __shfl(idx, jB);
            const bool okA = jA < m;
            const bool okB = jB < m;
            uint4 vA = ((const uint4*)(y + (size_t)sA * 64))[cq];
            uint4 vB = ((const uint4*)(y + (size_t)sB * 64))[cq];
            vA.x = okA ? vA.x : 0u; vA.y = okA ? vA.y : 0u;
            vA.z = okA ? vA.z : 0u; vA.w = okA ? vA.w : 0u;
            vB.x = okB ? vB.x : 0u; vB.y = okB ? vB.y : 0u;
            vB.z = okB ? vB.z : 0u; vB.w = okB ? vB.w : 0u;
            acc_bf16x8(acc, vA);
            acc_bf16x8(acc, vB);
        }
    }
#pragma unroll
    for (int off = 8; off < 64; off <<= 1)
#pragma unroll
        for (int i = 0; i < 8; i++) acc[i] += __shfl_xor(acc[i], off);

    float self[8];
#pragma unroll
    for (int i = 0; i < 8; i++) self[i] = 0.f;
    acc_bf16x8(self, ((const uint4*)(y + (size_t)node * 64))[cq]);
    const float di = dinv[node];
    float bb[8];
#pragma unroll
    for (int i = 0; i < 8; i++) bb[i] = 0.f;
    if (real) {
        const float4 bv0 = *(const float4*)(b + cq * 8);
        const float4 bv1 = *(const float4*)(b + cq * 8 + 4);
        bb[0] = bv0.x; bb[1] = bv0.y; bb[2] = bv0.z; bb[3] = bv0.w;
        bb[4] = bv1.x; bb[5] = bv1.y; bb[6] = bv1.z; bb[7] = bv1.w;
    }
    float h[8];
#pragma unroll
    for (int i = 0; i < 8; i++) h[i] = (acc[i] + self[i]) * di + bb[i];

    // log_softmax over the 40 real values, reduced across the 8-lane cluster
    float mx = -INFINITY;
    if (real)
#pragma unroll
        for (int i = 0; i < 8; i++) mx = fmaxf(mx, h[i]);
#pragma unroll
    for (int off = 1; off < 8; off <<= 1) mx = fmaxf(mx, __shfl_xor(mx, off));
    float es = 0.f;
    if (real)
#pragma unroll
        for (int i = 0; i < 8; i++) es += __expf(h[i] - mx);
#pragma unroll
    for (int off = 1; off < 8; off <<= 1) es += __shfl_xor(es, off);
    const float ls = mx + __logf(es);

    if (l < 5) {   // lanes 0..4 of cluster 0 hold channels 0..39
        float4 o0, o1;
        o0.x = h[0] - ls; o0.y = h[1] - ls; o0.z = h[2] - ls; o0.w = h[3] - ls;
        o1.x = h[4] - ls; o1.y = h[5] - ls; o1.z = h[6] - ls; o1.w = h[7] - ls;
        *(float4*)(out + (size_t)node * 40 + l * 8) = o0;
        *(float4*)(out + (size_t)node * 40 + l * 8 + 4) = o1;
    }
}

// ---------------- launch ----------------

extern "C" void kernel_launch(void* const* d_in, const int* in_sizes, int n_in,
                              void* d_out, int out_size, void* d_ws, size_t ws_size,
                              hipStream_t stream) {
    const float* x  = (const float*)d_in[0];
    const int* edges = (const int*)d_in[1];
    const float* W1 = (const float*)d_in[2];
    const float* b1 = (const float*)d_in[3];
    const float* W2 = (const float*)d_in[4];
    const float* b2 = (const float*)d_in[5];
    float* out = (float*)d_out;

    const int n = NN;
    const int E = in_sizes[1] / 2;

    char* ws = (char*)d_ws;
    size_t off = 0;
    auto alloc = [&](size_t bytes) -> void* {
        void* p = ws + off;
        off += (bytes + 255) & ~(size_t)255;
        return p;
    };
    int*            bcur    = (int*)alloc((size_t)NB * 4);
    unsigned*       bkt     = (unsigned*)alloc((size_t)NB * BCAP * 4);  // becomes nbr
    int*            row_off = (int*)alloc((size_t)n * 4);
    int*            deg     = (int*)alloc((size_t)n * 4);
    float*          dinv    = (float*)alloc((size_t)n * 4);
    float*          h1      = (float*)alloc((size_t)n * 64 * 4);
    unsigned short* y1      = (unsigned short*)alloc((size_t)n * 64 * 2);  // bf16, padded
    unsigned short* y2      = y1;   // y1 dead after agg64; reuse for layer-2 xw

    const int* src = edges;
    const int* dst = edges + E;

    hipMemsetAsync(bcur, 0, (size_t)NB * 4, stream);
    partition_kernel<<<NBLK_PART, 256, 0, stream>>>(src, dst, bcur, bkt, E);
    bucket_sort_kernel<<<NB, 256, 0, stream>>>(bcur, bkt, row_off, deg, dinv, n);

    const int gblk = (n + 127) / 128;   // 782

    // layer 1: y1 = bf16((x @ W1) * dinv) ; h1 = relu(agg(y1) * dinv + b1)
    gemm_kernel<256, 64><<<gblk, 128, 0, stream>>>(x, W1, dinv, y1, n);
    agg64_kernel<<<(n + 3) / 4, 256, 0, stream>>>(y1, row_off, deg, bkt, dinv, b1, h1, n);

    // layer 2: y2 = bf16((h1 @ W2) * dinv) ; out = log_softmax(agg(y2) * dinv + b2)
    gemm_kernel<64, 40><<<gblk, 128, 0, stream>>>(h1, W2, dinv, y2, n);
    agg40_lsm_kernel<<<(n + 3) / 4, 256, 0, stream>>>(y2, row_off, deg, bkt, dinv, b2, out, n);
}

// Round 7
// 367.001 us; speedup vs baseline: 7.6118x; 1.0721x over previous
//
#include <hip/hip_runtime.h>
#include <math.h>

#define NN 100000
#define NB 256        // coarse buckets
#define RANGE 392     // nodes per bucket (256*392 = 100352 >= 100000)
#define CAP 56        // staging entries per bucket per block
#define BCAP 13824    // bucket capacity (mean 12544, sigma ~112 -> 11 sigma)
#define NBLK_PART 512

typedef unsigned int uint;
typedef __attribute__((ext_vector_type(8))) short short8;
typedef __attribute__((ext_vector_type(4))) float f32x4;

// ---------------- partition: edges -> 256 dst-range buckets ----------------

__global__ __launch_bounds__(256) void partition_kernel(const int* __restrict__ src,
                                                        const int* __restrict__ dst,
                                                        int* __restrict__ bcur,
                                                        unsigned* __restrict__ bkt, int E) {
    __shared__ unsigned stage[NB * CAP];
    __shared__ int lcnt[NB];
    __shared__ int baseS[NB];
    for (int i = threadIdx.x; i < NB; i += 256) lcnt[i] = 0;
    __syncthreads();

    const int nq = E >> 2;
    const int stride = gridDim.x * blockDim.x;
    for (int q = blockIdx.x * blockDim.x + threadIdx.x; q < nq; q += stride) {
        const int4 s4 = ((const int4*)src)[q];
        const int4 d4 = ((const int4*)dst)[q];
#pragma unroll
        for (int k = 0; k < 4; k++) {
            const int s = (&s4.x)[k];
            const int d = (&d4.x)[k];
            const unsigned b = (unsigned)d / RANGE;
            const unsigned ent = ((unsigned)s << 9) | ((unsigned)d - b * RANGE);
            const int slot = atomicAdd(&lcnt[b], 1);
            if (slot < CAP) {
                stage[b * CAP + slot] = ent;
            } else {                       // rare overflow: direct global path
                const int pos = atomicAdd(&bcur[b], 1);
                if (pos < BCAP) bkt[(size_t)b * BCAP + pos] = ent;
            }
        }
    }
    // tail edges (E % 4)
    const int gid = blockIdx.x * blockDim.x + threadIdx.x;
    if (gid < (E & 3)) {
        const int e = (E & ~3) + gid;
        const int s = src[e], d = dst[e];
        const unsigned b = (unsigned)d / RANGE;
        const unsigned ent = ((unsigned)s << 9) | ((unsigned)d - b * RANGE);
        const int pos = atomicAdd(&bcur[b], 1);
        if (pos < BCAP) bkt[(size_t)b * BCAP + pos] = ent;
    }
    __syncthreads();

    // reserve all bucket bases in parallel (one atomic per bucket)
    if (threadIdx.x < NB) {
        const int c = min(lcnt[threadIdx.x], CAP);
        baseS[threadIdx.x] = (c > 0) ? atomicAdd(&bcur[threadIdx.x], c) : 0;
    }
    __syncthreads();

    // flush: contiguous chunk write per bucket
    const int w = threadIdx.x >> 6, l = threadIdx.x & 63;
    for (int b = w; b < NB; b += 4) {
        const int cnt = min(lcnt[b], CAP);
        const int base = baseS[b];
        for (int i = l; i < cnt; i += 64) {
            const int pos = base + i;
            if (pos < BCAP) bkt[(size_t)b * BCAP + pos] = stage[b * CAP + i];
        }
    }
}

// ---------------- per-bucket counting sort -> CSR (+deg/dinv) ----------------

__global__ __launch_bounds__(256) void bucket_sort_kernel(const int* __restrict__ bcur,
                                                          unsigned* __restrict__ bkt,
                                                          int* __restrict__ row_off,
                                                          int* __restrict__ deg,
                                                          float* __restrict__ dinv, int n) {
    __shared__ int sortedS[BCAP];
    __shared__ int cntS[RANGE];
    __shared__ int offS[RANGE];
    const int b = blockIdx.x;
    const int tid = threadIdx.x;
    unsigned* eb = bkt + (size_t)b * BCAP;
    const int m = min(bcur[b], BCAP);

    for (int i = tid; i < RANGE; i += 256) cntS[i] = 0;
    __syncthreads();
    for (int i = tid; i < m; i += 256) atomicAdd(&cntS[(int)(eb[i] & 511u)], 1);
    __syncthreads();

    // exclusive scan of cntS[0..RANGE) by wave 0
    if (tid < 64) {
        const int l = tid;
        int carry = 0;
        for (int base = 0; base < RANGE; base += 64) {
            const int i = base + l;
            const int c = (i < RANGE) ? cntS[i] : 0;
            int v = c;
#pragma unroll
            for (int off = 1; off < 64; off <<= 1) {
                const int t2 = __shfl_up(v, off);
                if (l >= off) v += t2;
            }
            if (i < RANGE) offS[i] = carry + v - c;
            carry += __shfl(v, 63);
        }
    }
    __syncthreads();

    // emit CSR metadata
    for (int i = tid; i < RANGE; i += 256) {
        const int node = b * RANGE + i;
        if (node < n) {
            row_off[node] = b * BCAP + offS[i];
            deg[node] = cntS[i];
            dinv[node] = rsqrtf((float)cntS[i] + 1.0f);   // +1 self-loop
        }
    }
    __syncthreads();

    // scatter into LDS (offS doubles as cursor now)
    for (int i = tid; i < m; i += 256) {
        const unsigned e = eb[i];
        const int pos = atomicAdd(&offS[(int)(e & 511u)], 1);
        sortedS[pos] = (int)(e >> 9);
    }
    __syncthreads();

    // in-place contiguous write-back (bkt segment becomes the nbr segment)
    for (int i = tid; i < m; i += 256) eb[i] = (unsigned)sortedS[i];
}

// bf16 helpers
__device__ inline uint pack_bf16(float a, float b) {
    uint ua = __float_as_uint(a), ub = __float_as_uint(b);
    ua = (ua + 0x7fffu + ((ua >> 16) & 1u)) >> 16;           // RNE, low half
    ub = (ub + 0x7fffu + ((ub >> 16) & 1u)) & 0xffff0000u;   // RNE, high half
    return ua | ub;
}
__device__ inline unsigned short bf16r(float f) {
    uint u = __float_as_uint(f);
    return (unsigned short)((u + 0x7fffu + ((u >> 16) & 1u)) >> 16);
}
__device__ inline void acc_bf16x8(float* acc, uint4 v) {
    const uint u[4] = {v.x, v.y, v.z, v.w};
#pragma unroll
    for (int i = 0; i < 4; i++) {
        acc[2 * i]     += __uint_as_float(u[i] << 16);
        acc[2 * i + 1] += __uint_as_float(u[i] & 0xffff0000u);
    }
}

// ---------------- MFMA GEMM: ybf16[r] = (x[r] @ W) * dinv[r], 64 ch padded ----------------
// 256 thr = 4 waves; block tile 128 rows x 64 ch; wave w owns rows w*32..+31
// (2 mtiles x 4 ntiles of 16x16, mfma_f32_16x16x32_bf16, K-chunks of 32).
// Wt[c][k] bf16 staged whole in LDS once; A chunk as[row][k] bf16 (stride 40,
// 16B-aligned frag reads). Next chunk's x float4s register-prefetched across
// the barrier. Layouts (learn_hip verified): A[m=lane&15][k=quad*8+j],
// B[k=quad*8+j][n=lane&15], D col=lane&15 row=quad*4+reg.

template <int K, int CREAL>
__global__ __launch_bounds__(256) void gemm_mfma_kernel(const float* __restrict__ x,
                                                        const float* __restrict__ W,
                                                        const float* __restrict__ dinv,
                                                        unsigned short* __restrict__ y,
                                                        int n) {
    constexpr int KP = K + 8;                 // wt row stride (bf16); *2B = mult of 16 ✓
    __shared__ unsigned short wt[64 * KP];    // W^T, channels padded to 64 with zeros
    __shared__ unsigned short as[128 * 40];   // A chunk, stride 40 bf16 = 80 B
    const int t = threadIdx.x;
    const int l = t & 63;
    const int w = t >> 6;                     // wave 0..3
    const int lane15 = l & 15;
    const int quad = l >> 4;                  // 0..3
    const int row0 = blockIdx.x * 128;

    // stage Wt (one-time). idx over K*16 float4-chunks of W rows.
    for (int idx = t; idx < K * 16; idx += 256) {
        const int k = idx >> 4;
        const int c4 = (idx & 15) * 4;
        float4 g = make_float4(0.f, 0.f, 0.f, 0.f);
        if (c4 < CREAL) g = *(const float4*)(W + (size_t)k * CREAL + c4);
        wt[(c4 + 0) * KP + k] = bf16r(g.x);
        wt[(c4 + 1) * KP + k] = bf16r(g.y);
        wt[(c4 + 2) * KP + k] = bf16r(g.z);
        wt[(c4 + 3) * KP + k] = bf16r(g.w);
    }

    f32x4 acc[2][4];
#pragma unroll
    for (int mt = 0; mt < 2; mt++)
#pragma unroll
        for (int nt = 0; nt < 4; nt++) acc[mt][nt] = (f32x4){0.f, 0.f, 0.f, 0.f};

    float4 g[4];
    // prefetch chunk 0
#pragma unroll
    for (int p = 0; p < 4; p++) {
        const int idx = t + p * 256;
        const int row = idx >> 3;
        const int kq = idx & 7;
        const int gr = min(row0 + row, n - 1);
        g[p] = *(const float4*)(x + (size_t)gr * K + kq * 4);
    }

    for (int kc = 0; kc < K; kc += 32) {
        __syncthreads();                      // as consumed (and wt staged, first iter)
#pragma unroll
        for (int p = 0; p < 4; p++) {
            const int idx = t + p * 256;
            const int row = idx >> 3;
            const int kq = idx & 7;
            uint2 pk;
            pk.x = pack_bf16(g[p].x, g[p].y);
            pk.y = pack_bf16(g[p].z, g[p].w);
            *(uint2*)(as + row * 40 + kq * 4) = pk;
        }
        if (kc + 32 < K) {                    // prefetch next chunk (in flight over mfma)
#pragma unroll
            for (int p = 0; p < 4; p++) {
                const int idx = t + p * 256;
                const int row = idx >> 3;
                const int kq = idx & 7;
                const int gr = min(row0 + row, n - 1);
                g[p] = *(const float4*)(x + (size_t)gr * K + kc + 32 + kq * 4);
            }
        }
        __syncthreads();

        short8 bf[4];
#pragma unroll
        for (int nt = 0; nt < 4; nt++)
            bf[nt] = *(const short8*)(wt + (nt * 16 + lane15) * KP + kc + quad * 8);
#pragma unroll
        for (int mt = 0; mt < 2; mt++) {
            const short8 af =
                *(const short8*)(as + (w * 32 + mt * 16 + lane15) * 40 + quad * 8);
#pragma unroll
            for (int nt = 0; nt < 4; nt++)
                acc[mt][nt] =
                    __builtin_amdgcn_mfma_f32_16x16x32_bf16(af, bf[nt], acc[mt][nt], 0, 0, 0);
        }
    }

    // epilogue: D[row=quad*4+r][col=lane15] per tile; scale by dinv, store bf16
#pragma unroll
    for (int mt = 0; mt < 2; mt++) {
#pragma unroll
        for (int r = 0; r < 4; r++) {
            const int row = row0 + w * 32 + mt * 16 + quad * 4 + r;
            if (row < n) {
                const float di = dinv[row];
#pragma unroll
                for (int nt = 0; nt < 4; nt++)
                    y[(size_t)row * 64 + nt * 16 + lane15] = bf16r(acc[mt][nt][r] * di);
            }
        }
    }
}

// ---------------- Aggregation, C=64 bf16 (+bias, ReLU), h1 out fp32 ----------------

__global__ __launch_bounds__(256) void agg64_kernel(const unsigned short* __restrict__ y,
                                                    const int* __restrict__ row_off,
                                                    const int* __restrict__ deg,
                                                    const unsigned* __restrict__ nbr,
                                                    const float* __restrict__ dinv,
                                                    const float* __restrict__ b,
                                                    float* __restrict__ out, int n) {
    int node = blockIdx.x * 4 + (threadIdx.x >> 6);
    if (node >= n) return;
    const int l = threadIdx.x & 63;
    const int g = l >> 3;            // 0..7
    const int cq = l & 7;            // 16B chunk within row; channels cq*8..cq*8+7

    const int start = row_off[node];
    const int dg = deg[node];

    float acc[8];
#pragma unroll
    for (int i = 0; i < 8; i++) acc[i] = 0.f;

    for (int base = 0; base < dg; base += 64) {
        const int m = min(64, dg - base);
        const int idx = (l < m) ? (int)nbr[start + base + l] : 0;
        for (int j0 = 0; j0 < m; j0 += 16) {
            const int jA = j0 + g;          // <= 55
            const int jB = j0 + 8 + g;      // <= 63
            const int sA = __shfl(idx, jA);
            const int sB = __shfl(idx, jB);
            const bool okA = jA < m;
            const bool okB = jB < m;
            uint4 vA = ((const uint4*)(y + (size_t)sA * 64))[cq];
            uint4 vB = ((const uint4*)(y + (size_t)sB * 64))[cq];
            vA.x = okA ? vA.x : 0u; vA.y = okA ? vA.y : 0u;
            vA.z = okA ? vA.z : 0u; vA.w = okA ? vA.w : 0u;
            vB.x = okB ? vB.x : 0u; vB.y = okB ? vB.y : 0u;
            vB.z = okB ? vB.z : 0u; vB.w = okB ? vB.w : 0u;
            acc_bf16x8(acc, vA);
            acc_bf16x8(acc, vB);
        }
    }
    // reduce across the 8 groups
#pragma unroll
    for (int off = 8; off < 64; off <<= 1)
#pragma unroll
        for (int i = 0; i < 8; i++) acc[i] += __shfl_xor(acc[i], off);

    // self-loop + scale + bias + relu; lanes 0..7 write fp32 h1
    float self[8];
#pragma unroll
    for (int i = 0; i < 8; i++) self[i] = 0.f;
    acc_bf16x8(self, ((const uint4*)(y + (size_t)node * 64))[cq]);
    const float di = dinv[node];
    const float4 bv0 = *(const float4*)(b + cq * 8);
    const float4 bv1 = *(const float4*)(b + cq * 8 + 4);
    const float bb[8] = {bv0.x, bv0.y, bv0.z, bv0.w, bv1.x, bv1.y, bv1.z, bv1.w};
    if (l < 8) {
        float4 o0, o1;
        o0.x = fmaxf((acc[0] + self[0]) * di + bb[0], 0.f);
        o0.y = fmaxf((acc[1] + self[1]) * di + bb[1], 0.f);
        o0.z = fmaxf((acc[2] + self[2]) * di + bb[2], 0.f);
        o0.w = fmaxf((acc[3] + self[3]) * di + bb[3], 0.f);
        o1.x = fmaxf((acc[4] + self[4]) * di + bb[4], 0.f);
        o1.y = fmaxf((acc[5] + self[5]) * di + bb[5], 0.f);
        o1.z = fmaxf((acc[6] + self[6]) * di + bb[6], 0.f);
        o1.w = fmaxf((acc[7] + self[7]) * di + bb[7], 0.f);
        *(float4*)(out + (size_t)node * 64 + l * 8) = o0;
        *(float4*)(out + (size_t)node * 64 + l * 8 + 4) = o1;
    }
}

// ---------------- Aggregation C=40 (bf16 rows padded to 64) + log_softmax ----------------

__global__ __launch_bounds__(256) void agg40_lsm_kernel(const unsigned short* __restrict__ y,
                                                        const int* __restrict__ row_off,
                                                        const int* __restrict__ deg,
                                                        const unsigned* __restrict__ nbr,
                                                        const float* __restrict__ dinv,
                                                        const float* __restrict__ b,
                                                        float* __restrict__ out, int n) {
    int node = blockIdx.x * 4 + (threadIdx.x >> 6);
    if (node >= n) return;
    const int l = threadIdx.x & 63;
    const int g = l >> 3;
    const int cq = l & 7;
    const bool real = (cq < 5);      // channels cq*8..cq*8+7 < 40

    const int start = row_off[node];
    const int dg = deg[node];

    float acc[8];
#pragma unroll
    for (int i = 0; i < 8; i++) acc[i] = 0.f;

    for (int base = 0; base < dg; base += 64) {
        const int m = min(64, dg - base);
        const int idx = (l < m) ? (int)nbr[start + base + l] : 0;
        for (int j0 = 0; j0 < m; j0 += 16) {
            const int jA = j0 + g;
            const int jB = j0 + 8 + g;
            const int sA = __shfl(idx, jA);
            const int sB = __shfl(idx, jB);
            const bool okA = jA < m;
            const bool okB = jB < m;
            uint4 vA = ((const uint4*)(y + (size_t)sA * 64))[cq];
            uint4 vB = ((const uint4*)(y + (size_t)sB * 64))[cq];
            vA.x = okA ? vA.x : 0u; vA.y = okA ? vA.y : 0u;
            vA.z = okA ? vA.z : 0u; vA.w = okA ? vA.w : 0u;
            vB.x = okB ? vB.x : 0u; vB.y = okB ? vB.y : 0u;
            vB.z = okB ? vB.z : 0u; vB.w = okB ? vB.w : 0u;
            acc_bf16x8(acc, vA);
            acc_bf16x8(acc, vB);
        }
    }
#pragma unroll
    for (int off = 8; off < 64; off <<= 1)
#pragma unroll
        for (int i = 0; i < 8; i++) acc[i] += __shfl_xor(acc[i], off);

    float self[8];
#pragma unroll
    for (int i = 0; i < 8; i++) self[i] = 0.f;
    acc_bf16x8(self, ((const uint4*)(y + (size_t)node * 64))[cq]);
    const float di = dinv[node];
    float bb[8];
#pragma unroll
    for (int i = 0; i < 8; i++) bb[i] = 0.f;
    if (real) {
        const float4 bv0 = *(const float4*)(b + cq * 8);
        const float4 bv1 = *(const float4*)(b + cq * 8 + 4);
        bb[0] = bv0.x; bb[1] = bv0.y; bb[2] = bv0.z; bb[3] = bv0.w;
        bb[4] = bv1.x; bb[5] = bv1.y; bb[6] = bv1.z; bb[7] = bv1.w;
    }
    float h[8];
#pragma unroll
    for (int i = 0; i < 8; i++) h[i] = (acc[i] + self[i]) * di + bb[i];

    // log_softmax over the 40 real values, reduced across the 8-lane cluster
    float mx = -INFINITY;
    if (real)
#pragma unroll
        for (int i = 0; i < 8; i++) mx = fmaxf(mx, h[i]);
#pragma unroll
    for (int off = 1; off < 8; off <<= 1) mx = fmaxf(mx, __shfl_xor(mx, off));
    float es = 0.f;
    if (real)
#pragma unroll
        for (int i = 0; i < 8; i++) es += __expf(h[i] - mx);
#pragma unroll
    for (int off = 1; off < 8; off <<= 1) es += __shfl_xor(es, off);
    const float ls = mx + __logf(es);

    if (l < 5) {   // lanes 0..4 of cluster 0 hold channels 0..39
        float4 o0, o1;
        o0.x = h[0] - ls; o0.y = h[1] - ls; o0.z = h[2] - ls; o0.w = h[3] - ls;
        o1.x = h[4] - ls; o1.y = h[5] - ls; o1.z = h[6] - ls; o1.w = h[7] - ls;
        *(float4*)(out + (size_t)node * 40 + l * 8) = o0;
        *(float4*)(out + (size_t)node * 40 + l * 8 + 4) = o1;
    }
}

// ---------------- launch ----------------

extern "C" void kernel_launch(void* const* d_in, const int* in_sizes, int n_in,
                              void* d_out, int out_size, void* d_ws, size_t ws_size,
                              hipStream_t stream) {
    const float* x  = (const float*)d_in[0];
    const int* edges = (const int*)d_in[1];
    const float* W1 = (const float*)d_in[2];
    const float* b1 = (const float*)d_in[3];
    const float* W2 = (const float*)d_in[4];
    const float* b2 = (const float*)d_in[5];
    float* out = (float*)d_out;

    const int n = NN;
    const int E = in_sizes[1] / 2;

    char* ws = (char*)d_ws;
    size_t off = 0;
    auto alloc = [&](size_t bytes) -> void* {
        void* p = ws + off;
        off += (bytes + 255) & ~(size_t)255;
        return p;
    };
    int*            bcur    = (int*)alloc((size_t)NB * 4);
    unsigned*       bkt     = (unsigned*)alloc((size_t)NB * BCAP * 4);  // becomes nbr
    int*            row_off = (int*)alloc((size_t)n * 4);
    int*            deg     = (int*)alloc((size_t)n * 4);
    float*          dinv    = (float*)alloc((size_t)n * 4);
    float*          h1      = (float*)alloc((size_t)n * 64 * 4);
    unsigned short* y1      = (unsigned short*)alloc((size_t)n * 64 * 2);  // bf16, padded
    unsigned short* y2      = y1;   // y1 dead after agg64; reuse for layer-2 xw

    const int* src = edges;
    const int* dst = edges + E;

    hipMemsetAsync(bcur, 0, (size_t)NB * 4, stream);
    partition_kernel<<<NBLK_PART, 256, 0, stream>>>(src, dst, bcur, bkt, E);
    bucket_sort_kernel<<<NB, 256, 0, stream>>>(bcur, bkt, row_off, deg, dinv, n);

    const int gblk = (n + 127) / 128;   // 782

    // layer 1: y1 = bf16((x @ W1) * dinv) ; h1 = relu(agg(y1) * dinv + b1)
    gemm_mfma_kernel<256, 64><<<gblk, 256, 0, stream>>>(x, W1, dinv, y1, n);
    agg64_kernel<<<(n + 3) / 4, 256, 0, stream>>>(y1, row_off, deg, bkt, dinv, b1, h1, n);

    // layer 2: y2 = bf16((h1 @ W2) * dinv) ; out = log_softmax(agg(y2) * dinv + b2)
    gemm_mfma_kernel<64, 40><<<gblk, 256, 0, stream>>>(h1, W2, dinv, y2, n);
    agg40_lsm_kernel<<<(n + 3) / 4, 256, 0, stream>>>(y2, row_off, deg, bkt, dinv, b2, out, n);
}